// Round 6
// baseline (3411.550 us; speedup 1.0000x reference)
//
#include <hip/hip_runtime.h>
#include <math.h>

#define N_VOX 98304
#define C_DIM 256
#define H_NUM 8
#define T_WIN 64
#define V_VAL 48
#define W_NUM 2048
#define F_DIM 1024
#define D_HEAD 32

typedef __attribute__((ext_vector_type(8))) short bf16x8;   // MFMA A/B operand (8 bf16, 4 VGPR)
typedef __attribute__((ext_vector_type(4))) float f32x4;    // MFMA C/D operand
typedef __attribute__((ext_vector_type(8))) unsigned short u16x8;

__device__ __forceinline__ float4 ld4(const float* p) {
    return *reinterpret_cast<const float4*>(p);
}

// fragment-slot swizzle: involution (XOR bits[2:0] with bits[5:3]) — spreads
// the 8-chunk aliasing across bank groups; same map on write and read.
__device__ __forceinline__ int swz(int f) { return f ^ ((f >> 3) & 7); }

// split x ~= hi + lo, both bf16 (truncation); x - hi is exact (Sterbenz), so
// hi + lo reproduces x to ~2^-17 rel; dropped al*bl MFMA term ~2^-16.
__device__ __forceinline__ void split8(const float4& x, const float4& y, u16x8& h, u16x8& l) {
    float v[8] = {x.x, x.y, x.z, x.w, y.x, y.y, y.z, y.w};
#pragma unroll
    for (int e = 0; e < 8; e++) {
        unsigned int u = __float_as_uint(v[e]);
        h[e] = (unsigned short)(u >> 16);
        float r = v[e] - __uint_as_float(u & 0xFFFF0000u);
        l[e] = (unsigned short)(__float_as_uint(r) >> 16);
    }
}

// ---------------------------------------------------------------------------
// Weight pre-conversion: fp32 [Nc][K] row-major -> fragment-ordered hi/lo bf16.
// Fragment (nb, kb) covers cols nb*16..+16, k kb*32..+32 of W; element order:
//   elem((nb*KB+kb)*512 + lane*8 + j) = W[nb*16 + (lane&15)][kb*32 + (lane>>4)*8 + j]
// so a wave's b128 load at (frag*64+lane)*8 is exactly the MFMA B-fragment
// (B layout: lane l supplies B[k=(l>>4)*8+j][col=l&15], W stored [col][k]).
// Segment elem offsets in the hi/lo arenas:
//   ipw l: l*196608 ; opw: 393216 + l*65536 ; l1w: 524288 + l*262144 ;
//   l2w: 1048576 + l*262144 ; total 1572864 elems per arena.
// ---------------------------------------------------------------------------
__global__ __launch_bounds__(256)
void conv_weights(const float* __restrict__ ipw, const float* __restrict__ opw,
                  const float* __restrict__ l1w, const float* __restrict__ l2w,
                  unsigned short* __restrict__ whi, unsigned short* __restrict__ wlo)
{
    for (int c = blockIdx.x * 256 + threadIdx.x; c < 196608; c += gridDim.x * 256) {
        const int e = c * 8;
        const float* src; int base, K;
        if      (e <  196608) { src = ipw;          base = 0;       K = 256;  }
        else if (e <  393216) { src = ipw + 196608; base = 196608;  K = 256;  }
        else if (e <  458752) { src = opw;          base = 393216;  K = 256;  }
        else if (e <  524288) { src = opw + 65536;  base = 458752;  K = 256;  }
        else if (e <  786432) { src = l1w;          base = 524288;  K = 256;  }
        else if (e < 1048576) { src = l1w + 262144; base = 786432;  K = 256;  }
        else if (e < 1310720) { src = l2w;          base = 1048576; K = 1024; }
        else                  { src = l2w + 262144; base = 1310720; K = 1024; }
        const int cc = c - (base >> 3);
        const int lane = cc & 63;
        const int fk = cc >> 6;
        const int KB = K >> 5;
        const int kb = fk % KB;
        const int nb = fk / KB;
        const int srow = nb * 16 + (lane & 15);
        const int scol = kb * 32 + (lane >> 4) * 8;
        float4 x = ld4(src + (size_t)srow * K + scol);
        float4 y = ld4(src + (size_t)srow * K + scol + 4);
        u16x8 h, l;
        split8(x, y, h, l);
        *reinterpret_cast<u16x8*>(whi + e) = h;
        *reinterpret_cast<u16x8*>(wlo + e) = l;
    }
}

// ---------------------------------------------------------------------------
// Split-bf16 MFMA GEMM (NT): out[r,c] = sum_k A[r,k] * W[c,k] + bias[c]
// 128x256 tile, BK=32, 512 threads = 8 waves (2 row x 4 col), wave = 64x64
// = 4x4 frags of 16x16x32 bf16 MFMA.
// A: fp32 global (MODE1: gathered feat + pos) -> split hi/lo -> LDS frag-major,
//    with next-K-step register prefetch issued under the MFMA block (T14-lite).
// W: pre-converted fragment-ordered hi/lo bf16, loaded register-direct (L2-hot).
// 3-pass: acc += ah*wl + al*wh + ah*wh  (al*wl dropped, ~2^-16).
// MODE 0: plain   1: qkv (blockIdx.y picks q/k/v)   2: scatter to voxel   3: gelu
// ---------------------------------------------------------------------------
template<int MODE>
__global__ __launch_bounds__(512)
void gemm_mfma(const float* __restrict__ A, const float* __restrict__ feat,
               const int* __restrict__ winds, const float* __restrict__ pos,
               const unsigned short* __restrict__ Whi, const unsigned short* __restrict__ Wlo,
               const float* __restrict__ bias,
               float* __restrict__ out0, float* __restrict__ out1, float* __restrict__ out2,
               int Nc, int K)
{
    __shared__ unsigned short sAh[512 * 8];   // 8 KiB: 128 rows x 32 k, 8-elem chunks
    __shared__ unsigned short sAl[512 * 8];   // 8 KiB
    const int tid = threadIdx.x;
    const int m0 = blockIdx.x * 128;
    const int n0 = blockIdx.y * 256;
    const int KB = K >> 5;

    float* outp = out0;
    bool addpos = false;
    if (MODE == 1) {
        int grp = blockIdx.y;                 // 0:q 1:k 2:v — block-uniform
        outp = (grp == 0) ? out0 : (grp == 1 ? out1 : out2);
        addpos = (grp < 2);
    }

    // staging map: thread -> (row sr, k-octet sq); one split8 chunk per thread
    const int sr = tid >> 2;                  // 0..127
    const int sq = tid & 3;                   // k-octet within BK=32
    size_t ga, gp = 0;
    const float* Asrc;
    if (MODE == 1) {
        int r = m0 + sr;
        int w = r / V_VAL, v = r - w * V_VAL;
        int t = w * T_WIN + v;
        ga = (size_t)winds[t] * C_DIM;
        gp = (size_t)t * C_DIM;
        Asrc = feat;
    } else {
        ga = (size_t)(m0 + sr) * K;
        Asrc = A;
    }

    // compute map: 8 waves, 2 row-waves x 4 col-waves
    const int wid = tid >> 6, lane = tid & 63;
    const int wm = wid & 1, wn = wid >> 1;    // wn 0..3
    const int lr = lane & 15, lg = lane >> 4;

    f32x4 acc[4][4];
#pragma unroll
    for (int i = 0; i < 4; i++)
#pragma unroll
        for (int j = 0; j < 4; j++) acc[i][j] = (f32x4){0.f, 0.f, 0.f, 0.f};

    // prologue: load A chunk for k0 = 0
    float4 a0 = ld4(Asrc + ga + sq * 8);
    float4 a1 = ld4(Asrc + ga + sq * 8 + 4);
    if (MODE == 1 && addpos) {
        float4 p0 = ld4(pos + gp + sq * 8);
        float4 p1 = ld4(pos + gp + sq * 8 + 4);
        a0.x += p0.x; a0.y += p0.y; a0.z += p0.z; a0.w += p0.w;
        a1.x += p1.x; a1.y += p1.y; a1.z += p1.z; a1.w += p1.w;
    }

    for (int k0 = 0; k0 < K; k0 += 32) {
        u16x8 h0, l0;
        split8(a0, a1, h0, l0);
        const int f0 = sr * 4 + sq;           // chunk = row*4 + k/8
        __syncthreads();                      // prev iteration's frag reads done
        *reinterpret_cast<u16x8*>(sAh + swz(f0) * 8) = h0;
        *reinterpret_cast<u16x8*>(sAl + swz(f0) * 8) = l0;
        __syncthreads();

        // prefetch next K-step's A chunk; latency hides under the MFMA block
        if (k0 + 32 < K) {
            const float* ap = Asrc + ga + k0 + 32 + sq * 8;
            a0 = ld4(ap); a1 = ld4(ap + 4);
            if (MODE == 1 && addpos) {
                const float* pp = pos + gp + k0 + 32 + sq * 8;
                float4 p0 = ld4(pp), p1 = ld4(pp + 4);
                a0.x += p0.x; a0.y += p0.y; a0.z += p0.z; a0.w += p0.w;
                a1.x += p1.x; a1.y += p1.y; a1.z += p1.z; a1.w += p1.w;
            }
        }

        // A fragments: lane l takes A[row16=lr][k=lg*8..+8]
        bf16x8 a_h[4], a_l[4];
#pragma unroll
        for (int i = 0; i < 4; i++) {
            int f = (wm * 64 + i * 16 + lr) * 4 + lg;
            int o = swz(f) * 8;
            a_h[i] = *reinterpret_cast<const bf16x8*>(sAh + o);
            a_l[i] = *reinterpret_cast<const bf16x8*>(sAl + o);
        }

        const int kb = k0 >> 5;
#pragma unroll
        for (int j = 0; j < 4; j++) {
            const int nb = (n0 + wn * 64 + j * 16) >> 4;
            const size_t boff = ((size_t)(nb * KB + kb) * 64 + lane) * 8;
            bf16x8 b_h = *reinterpret_cast<const bf16x8*>(Whi + boff);
            bf16x8 b_l = *reinterpret_cast<const bf16x8*>(Wlo + boff);
#pragma unroll
            for (int i = 0; i < 4; i++) {
                acc[i][j] = __builtin_amdgcn_mfma_f32_16x16x32_bf16(a_h[i], b_l, acc[i][j], 0, 0, 0);
                acc[i][j] = __builtin_amdgcn_mfma_f32_16x16x32_bf16(a_l[i], b_h, acc[i][j], 0, 0, 0);
                acc[i][j] = __builtin_amdgcn_mfma_f32_16x16x32_bf16(a_h[i], b_h, acc[i][j], 0, 0, 0);
            }
        }
    }

    // epilogue: D[col = lane&15, row = 4*(lane>>4)+reg] (m89-verified layout)
    float bj[4];
#pragma unroll
    for (int j = 0; j < 4; j++) bj[j] = bias[n0 + wn * 64 + j * 16 + lr];
    const int cbase = ((MODE == 1) ? 0 : n0) + wn * 64 + lr;

#pragma unroll
    for (int i = 0; i < 4; i++) {
        size_t rbase[4];
#pragma unroll
        for (int rg = 0; rg < 4; rg++) {
            int rr = m0 + wm * 64 + i * 16 + lg * 4 + rg;
            if (MODE == 2) {
                int w = rr / V_VAL, vv = rr - w * V_VAL;
                rbase[rg] = (size_t)winds[w * T_WIN + vv] * C_DIM;
            } else if (MODE == 1) {
                rbase[rg] = (size_t)rr * C_DIM;
            } else {
                rbase[rg] = (size_t)rr * (size_t)Nc;
            }
        }
#pragma unroll
        for (int j = 0; j < 4; j++) {
#pragma unroll
            for (int rg = 0; rg < 4; rg++) {
                float t = acc[i][j][rg] + bj[j];
                if (MODE == 3) t = 0.5f * t * (1.f + erff(t * 0.70710678118654752f));
                outp[rbase[rg] + cbase + j * 16] = t;
            }
        }
    }
}

// one block per (window, head); q/k/v are [N, C] window-major fp32; o overwrites q
__global__ __launch_bounds__(256)
void attn_win(float* __restrict__ q, const float* __restrict__ k, const float* __restrict__ v)
{
    __shared__ float qs[V_VAL][D_HEAD + 1];
    __shared__ float ks[V_VAL][D_HEAD + 1];
    __shared__ float vs[V_VAL][D_HEAD + 1];
    __shared__ float ss[V_VAL][V_VAL + 1];
    const int tid = threadIdx.x;
    const int wid = blockIdx.x >> 3;
    const int h = blockIdx.x & 7;
    const size_t base = (size_t)(wid * V_VAL) * C_DIM + h * D_HEAD;

    for (int e = tid; e < V_VAL * D_HEAD; e += 256) {
        int t = e >> 5, d = e & 31;
        size_t src = base + (size_t)t * C_DIM + d;
        qs[t][d] = q[src];
        ks[t][d] = k[src];
        vs[t][d] = v[src];
    }
    __syncthreads();

    const int si = (tid >> 4) * 3, sj = (tid & 15) * 3;
    float a00=0,a01=0,a02=0,a10=0,a11=0,a12=0,a20=0,a21=0,a22=0;
#pragma unroll
    for (int kk = 0; kk < D_HEAD; kk++) {
        float q0 = qs[si][kk], q1 = qs[si+1][kk], q2 = qs[si+2][kk];
        float k0 = ks[sj][kk], k1 = ks[sj+1][kk], k2 = ks[sj+2][kk];
        a00 += q0*k0; a01 += q0*k1; a02 += q0*k2;
        a10 += q1*k0; a11 += q1*k1; a12 += q1*k2;
        a20 += q2*k0; a21 += q2*k1; a22 += q2*k2;
    }
    const float scale = 0.17677669529663687f;
    ss[si  ][sj] = a00*scale; ss[si  ][sj+1] = a01*scale; ss[si  ][sj+2] = a02*scale;
    ss[si+1][sj] = a10*scale; ss[si+1][sj+1] = a11*scale; ss[si+1][sj+2] = a12*scale;
    ss[si+2][sj] = a20*scale; ss[si+2][sj+1] = a21*scale; ss[si+2][sj+2] = a22*scale;
    __syncthreads();

    if (tid < V_VAL) {
        float m = -1e30f;
        for (int j = 0; j < V_VAL; j++) m = fmaxf(m, ss[tid][j]);
        float sum = 0.f;
        for (int j = 0; j < V_VAL; j++) {
            float e = expf(ss[tid][j] - m);
            ss[tid][j] = e;
            sum += e;
        }
        float inv = 1.f / sum;
        for (int j = 0; j < V_VAL; j++) ss[tid][j] *= inv;
    }
    __syncthreads();

    const int oi = (tid >> 4) * 3, oj = (tid & 15) * 2;
    float o00=0,o01=0,o10=0,o11=0,o20=0,o21=0;
#pragma unroll 4
    for (int t = 0; t < V_VAL; t++) {
        float p0 = ss[oi][t], p1 = ss[oi+1][t], p2 = ss[oi+2][t];
        float v0 = vs[t][oj], v1 = vs[t][oj+1];
        o00 += p0*v0; o01 += p0*v1;
        o10 += p1*v0; o11 += p1*v1;
        o20 += p2*v0; o21 += p2*v1;
    }
    q[base + (size_t)(oi  ) * C_DIM + oj] = o00; q[base + (size_t)(oi  ) * C_DIM + oj + 1] = o01;
    q[base + (size_t)(oi+1) * C_DIM + oj] = o10; q[base + (size_t)(oi+1) * C_DIM + oj + 1] = o11;
    q[base + (size_t)(oi+2) * C_DIM + oj] = o20; q[base + (size_t)(oi+2) * C_DIM + oj + 1] = o21;
}

// out = LayerNorm(x + r) * s + b ; one wave per 256-wide row (in-place safe)
__global__ __launch_bounds__(256)
void ln_res(const float* __restrict__ x, const float* __restrict__ r,
            const float* __restrict__ s, const float* __restrict__ b,
            float* __restrict__ out)
{
    const int row = blockIdx.x * 4 + (threadIdx.x >> 6);
    const int lane = threadIdx.x & 63;
    const size_t off = (size_t)row * C_DIM + lane * 4;
    float4 xv = ld4(x + off);
    float4 rv = ld4(r + off);
    float tx = xv.x + rv.x, ty = xv.y + rv.y, tz = xv.z + rv.z, tw = xv.w + rv.w;
    float sum = tx + ty + tz + tw;
#pragma unroll
    for (int m = 32; m >= 1; m >>= 1) sum += __shfl_xor(sum, m, 64);
    const float mean = sum * (1.0f / 256.0f);
    float dx = tx - mean, dy = ty - mean, dz = tz - mean, dw = tw - mean;
    float sq = dx*dx + dy*dy + dz*dz + dw*dw;
#pragma unroll
    for (int m = 32; m >= 1; m >>= 1) sq += __shfl_xor(sq, m, 64);
    const float inv = rsqrtf(sq * (1.0f / 256.0f) + 1e-5f);
    const int c = lane * 4;
    float4 sv = ld4(s + c);
    float4 bv = ld4(b + c);
    float4 o;
    o.x = dx * inv * sv.x + bv.x;
    o.y = dy * inv * sv.y + bv.y;
    o.z = dz * inv * sv.z + bv.z;
    o.w = dw * inv * sv.w + bv.w;
    *reinterpret_cast<float4*>(out + off) = o;
}

extern "C" void kernel_launch(void* const* d_in, const int* in_sizes, int n_in,
                              void* d_out, int out_size, void* d_ws, size_t ws_size,
                              hipStream_t stream)
{
    const float* feat_in = (const float*)d_in[0];
    const float* pos     = (const float*)d_in[1];
    const int*   winds   = (const int*)d_in[2];
    // d_in[3] = padding_mask (unused: pad iff t >= V)
    const float* ipw = (const float*)d_in[4];
    const float* ipb = (const float*)d_in[5];
    const float* opw = (const float*)d_in[6];
    const float* opb = (const float*)d_in[7];
    const float* l1w = (const float*)d_in[8];
    const float* l1b = (const float*)d_in[9];
    const float* l2w = (const float*)d_in[10];
    const float* l2b = (const float*)d_in[11];
    const float* n1s = (const float*)d_in[12];
    const float* n1b = (const float*)d_in[13];
    const float* n2s = (const float*)d_in[14];
    const float* n2b = (const float*)d_in[15];

    float* feat_out = (float*)d_out;
    float* ws = (float*)d_ws;

    // Arena (peak 3*nc + 6 MB ~= 308 MB):
    //   attn phase: q(0..nc) kbuf(nc..2nc) vbuf(2nc..3nc); aseq reuses kbuf slot
    //               (K is dead after attn_win); LN1 consumes aseq.
    //   ffn phase (2 half-N chunks): mid(0..2nc) tmp(2nc..2.5nc) — overwrites
    //               only dead q/aseq/vbuf regions.
    //   weights: hi/lo arenas at 3nc (written once per call, read-only after).
    const size_t nc = (size_t)N_VOX * C_DIM;   // 25165824 floats
    float* q    = ws;
    float* kbuf = ws + nc;
    float* vbuf = ws + 2 * nc;
    float* aseq = kbuf;
    float* mid  = ws;
    float* tmp  = ws + 2 * nc;

    unsigned short* whi = (unsigned short*)(ws + 3 * nc);
    unsigned short* wlo = whi + 1572864;

    const dim3 blk256(256);
    const dim3 blk512(512);
    const int NH = N_VOX / 2;                  // FFN chunk rows

    // weights -> fragment-ordered split bf16 (every call; ws is re-poisoned)
    conv_weights<<<dim3(768), blk256, 0, stream>>>(ipw, opw, l1w, l2w, whi, wlo);

    for (int l = 0; l < 2; l++) {
        const float* fin = (l == 0) ? feat_in : feat_out;
        const int*   wl  = winds + (size_t)l * W_NUM * T_WIN;
        const float* pl  = pos + (size_t)l * W_NUM * T_WIN * C_DIM;

        const unsigned short* ipw_h = whi + (size_t)l * 196608;
        const unsigned short* ipw_l = wlo + (size_t)l * 196608;
        const unsigned short* opw_h = whi + 393216 + (size_t)l * 65536;
        const unsigned short* opw_l = wlo + 393216 + (size_t)l * 65536;
        const unsigned short* l1w_h = whi + 524288 + (size_t)l * 262144;
        const unsigned short* l1w_l = wlo + 524288 + (size_t)l * 262144;
        const unsigned short* l2w_h = whi + 1048576 + (size_t)l * 262144;
        const unsigned short* l2w_l = wlo + 1048576 + (size_t)l * 262144;

        // QKV projection (gather + pos fused); blockIdx.y = {q,k,v}
        gemm_mfma<1><<<dim3(768, 3), blk512, 0, stream>>>(
            nullptr, fin, wl, pl, ipw_h, ipw_l,
            ipb + (size_t)l * 3 * C_DIM, q, kbuf, vbuf, 3 * C_DIM, C_DIM);

        // windowed attention (o overwrites q)
        attn_win<<<dim3(W_NUM * H_NUM), blk256, 0, stream>>>(q, kbuf, vbuf);

        // out projection, scattered back to sequence order (aseq = kbuf slot)
        gemm_mfma<2><<<dim3(768, 1), blk512, 0, stream>>>(
            q, nullptr, wl, nullptr, opw_h, opw_l,
            opb + (size_t)l * C_DIM, aseq, nullptr, nullptr, C_DIM, C_DIM);

        // LN1(feat + attn)
        ln_res<<<dim3(N_VOX / 4), blk256, 0, stream>>>(
            fin, aseq, n1s + (size_t)l * C_DIM, n1b + (size_t)l * C_DIM, feat_out);

        // FFN in two half-N chunks to cap workspace
        for (int c = 0; c < 2; c++) {
            const float* fchunk = feat_out + (size_t)c * NH * C_DIM;
            // up + gelu: [NH, C] x [F, C]^T -> mid [NH, F]
            gemm_mfma<3><<<dim3(NH / 128, F_DIM / 256), blk512, 0, stream>>>(
                fchunk, nullptr, nullptr, nullptr, l1w_h, l1w_l,
                l1b + (size_t)l * F_DIM, mid, nullptr, nullptr, F_DIM, C_DIM);
            // down: [NH, F] x [C, F]^T -> tmp [NH, C] (single col-block)
            gemm_mfma<0><<<dim3(NH / 128, 1), blk512, 0, stream>>>(
                mid, nullptr, nullptr, nullptr, l2w_h, l2w_l,
                l2b + (size_t)l * C_DIM, tmp, nullptr, nullptr, C_DIM, F_DIM);
            // LN2(feat + ffn) on the chunk
            ln_res<<<dim3(NH / 4), blk256, 0, stream>>>(
                fchunk, tmp, n2s + (size_t)l * C_DIM, n2b + (size_t)l * C_DIM,
                feat_out + (size_t)c * NH * C_DIM);
        }
    }
}

// Round 8
// 2736.403 us; speedup vs baseline: 1.2467x; 1.2467x over previous
//
#include <hip/hip_runtime.h>
#include <math.h>

#define N_VOX 98304
#define C_DIM 256
#define H_NUM 8
#define T_WIN 64
#define V_VAL 48
#define W_NUM 2048
#define F_DIM 1024
#define D_HEAD 32

typedef __attribute__((ext_vector_type(8))) short bf16x8;   // MFMA A/B operand (8 bf16, 4 VGPR)
typedef __attribute__((ext_vector_type(4))) float f32x4;    // MFMA C/D operand
typedef __attribute__((ext_vector_type(8))) unsigned short u16x8;

__device__ __forceinline__ float4 ld4(const float* p) {
    return *reinterpret_cast<const float4*>(p);
}

// fragment-slot swizzle: involution (XOR bits[2:0] with bits[5:3]) — spreads
// the 8-chunk aliasing across bank groups; same map on write and read.
__device__ __forceinline__ int swz(int f) { return f ^ ((f >> 3) & 7); }

// split x ~= hi + lo, both bf16 (truncation); x - hi is exact, so hi + lo
// reproduces x to ~2^-17 rel; dropped al*bl MFMA term ~2^-16.
__device__ __forceinline__ void split8(const float4& x, const float4& y, u16x8& h, u16x8& l) {
    float v[8] = {x.x, x.y, x.z, x.w, y.x, y.y, y.z, y.w};
#pragma unroll
    for (int e = 0; e < 8; e++) {
        unsigned int u = __float_as_uint(v[e]);
        h[e] = (unsigned short)(u >> 16);
        float r = v[e] - __uint_as_float(u & 0xFFFF0000u);
        l[e] = (unsigned short)(__float_as_uint(r) >> 16);
    }
}

// ---------------------------------------------------------------------------
// Weight pre-conversion: fp32 [Nc][K] row-major -> fragment-ordered hi/lo bf16.
//   elem((nb*KB+kb)*512 + lane*8 + j) = W[nb*16 + (lane&15)][kb*32 + (lane>>4)*8 + j]
// A wave's b128 load at (frag*64+lane)*8 is exactly the MFMA B-fragment.
// Segment elem offsets: ipw l: l*196608 ; opw: 393216+l*65536 ;
// l1w: 524288+l*262144 ; l2w: 1048576+l*262144 ; total 1572864 per arena.
// ---------------------------------------------------------------------------
__global__ __launch_bounds__(256)
void conv_weights(const float* __restrict__ ipw, const float* __restrict__ opw,
                  const float* __restrict__ l1w, const float* __restrict__ l2w,
                  unsigned short* __restrict__ whi, unsigned short* __restrict__ wlo)
{
    for (int c = blockIdx.x * 256 + threadIdx.x; c < 196608; c += gridDim.x * 256) {
        const int e = c * 8;
        const float* src; int base, K;
        if      (e <  196608) { src = ipw;          base = 0;       K = 256;  }
        else if (e <  393216) { src = ipw + 196608; base = 196608;  K = 256;  }
        else if (e <  458752) { src = opw;          base = 393216;  K = 256;  }
        else if (e <  524288) { src = opw + 65536;  base = 458752;  K = 256;  }
        else if (e <  786432) { src = l1w;          base = 524288;  K = 256;  }
        else if (e < 1048576) { src = l1w + 262144; base = 786432;  K = 256;  }
        else if (e < 1310720) { src = l2w;          base = 1048576; K = 1024; }
        else                  { src = l2w + 262144; base = 1310720; K = 1024; }
        const int cc = c - (base >> 3);
        const int lane = cc & 63;
        const int fk = cc >> 6;
        const int KB = K >> 5;
        const int kb = fk % KB;
        const int nb = fk / KB;
        const int srow = nb * 16 + (lane & 15);
        const int scol = kb * 32 + (lane >> 4) * 8;
        float4 x = ld4(src + (size_t)srow * K + scol);
        float4 y = ld4(src + (size_t)srow * K + scol + 4);
        u16x8 h, l;
        split8(x, y, h, l);
        *reinterpret_cast<u16x8*>(whi + e) = h;
        *reinterpret_cast<u16x8*>(wlo + e) = l;
    }
}

// ---------------------------------------------------------------------------
// Split-bf16 MFMA GEMM (NT): out[r,c] = sum_k A[r,k] * W[c,k] + bias[c]
// 128x128 tile, BK=32, 256 threads = 4 waves (2x2), wave = 64x64
// = 4x4 frags of 16x16x32 bf16 MFMA. ~144 regs -> 3 waves/SIMD, 3 blocks/CU.
// A: fp32 global (MODE1: gathered feat+pos) -> split hi/lo -> LDS frag-major,
//    DOUBLE-BUFFERED (one barrier per K-step), next-step global prefetch.
// W: pre-converted fragment-ordered hi/lo bf16, register-direct (L2-hot).
// 3-pass: acc += ah*wl + al*wh + ah*wh  (al*wl dropped, ~2^-16).
// MODE 0: plain   1: qkv   2: scatter to voxel   3: gelu
// ---------------------------------------------------------------------------
template<int MODE>
__global__ __launch_bounds__(256, 3)
void gemm_mfma(const float* __restrict__ A, const float* __restrict__ feat,
               const int* __restrict__ winds, const float* __restrict__ pos,
               const unsigned short* __restrict__ Whi, const unsigned short* __restrict__ Wlo,
               const float* __restrict__ bias,
               float* __restrict__ out0, float* __restrict__ out1, float* __restrict__ out2,
               int Nc, int K)
{
    __shared__ unsigned short sAh[2][512 * 8];   // 2 x 8 KiB: 128 rows x 32 k
    __shared__ unsigned short sAl[2][512 * 8];   // 2 x 8 KiB
    const int tid = threadIdx.x;
    const int m0 = blockIdx.x * 128;
    const int n0 = blockIdx.y * 128;
    const int KB = K >> 5;

    float* outp = out0;
    int ncol = n0;
    bool addpos = false;
    if (MODE == 1) {
        int grp = n0 >> 8;                    // BN=128 divides 256: grp uniform
        outp = (grp == 0) ? out0 : (grp == 1 ? out1 : out2);
        ncol = n0 & 255;
        addpos = (grp < 2);
    }

    // staging map: thread -> (row sr, k-half sh); 16 fp32 = 2 chunks per thread
    const int sr = tid >> 1;                  // 0..127
    const int sh = tid & 1;                   // k-half (16 floats) within BK=32
    size_t ga, gp = 0;
    const float* Asrc;
    if (MODE == 1) {
        int r = m0 + sr;
        int w = r / V_VAL, v = r - w * V_VAL;
        int t = w * T_WIN + v;
        ga = (size_t)winds[t] * C_DIM;
        gp = (size_t)t * C_DIM;
        Asrc = feat;
    } else {
        ga = (size_t)(m0 + sr) * K;
        Asrc = A;
    }

    // compute map: 4 waves, 2 row-waves x 2 col-waves
    const int wid = tid >> 6, lane = tid & 63;
    const int wm = wid & 1, wn = wid >> 1;
    const int lr = lane & 15, lg = lane >> 4;

    f32x4 acc[4][4];
#pragma unroll
    for (int i = 0; i < 4; i++)
#pragma unroll
        for (int j = 0; j < 4; j++) acc[i][j] = (f32x4){0.f, 0.f, 0.f, 0.f};

    // prologue: load + split A(k0=0), write buf 0
    float4 a0, a1, a2, a3;
    {
        const float* ap = Asrc + ga + sh * 16;
        a0 = ld4(ap); a1 = ld4(ap + 4); a2 = ld4(ap + 8); a3 = ld4(ap + 12);
        if (MODE == 1 && addpos) {
            const float* pp = pos + gp + sh * 16;
            float4 p0 = ld4(pp), p1 = ld4(pp + 4), p2 = ld4(pp + 8), p3 = ld4(pp + 12);
            a0.x += p0.x; a0.y += p0.y; a0.z += p0.z; a0.w += p0.w;
            a1.x += p1.x; a1.y += p1.y; a1.z += p1.z; a1.w += p1.w;
            a2.x += p2.x; a2.y += p2.y; a2.z += p2.z; a2.w += p2.w;
            a3.x += p3.x; a3.y += p3.y; a3.z += p3.z; a3.w += p3.w;
        }
    }
    const int f0 = sr * 4 + sh * 2;           // chunk = row*4 + k/8
    {
        u16x8 h0, l0, h1, l1;
        split8(a0, a1, h0, l0);
        split8(a2, a3, h1, l1);
        *reinterpret_cast<u16x8*>(sAh[0] + swz(f0) * 8) = h0;
        *reinterpret_cast<u16x8*>(sAl[0] + swz(f0) * 8) = l0;
        *reinterpret_cast<u16x8*>(sAh[0] + swz(f0 + 1) * 8) = h1;
        *reinterpret_cast<u16x8*>(sAl[0] + swz(f0 + 1) * 8) = l1;
    }
    __syncthreads();

    int cur = 0;
    for (int k0 = 0; k0 < K; k0 += 32) {
        const bool more = (k0 + 32 < K);
        // prefetch next K-step's A chunk (latency hides under this step)
        if (more) {
            const float* ap = Asrc + ga + k0 + 32 + sh * 16;
            a0 = ld4(ap); a1 = ld4(ap + 4); a2 = ld4(ap + 8); a3 = ld4(ap + 12);
            if (MODE == 1 && addpos) {
                const float* pp = pos + gp + k0 + 32 + sh * 16;
                float4 p0 = ld4(pp), p1 = ld4(pp + 4), p2 = ld4(pp + 8), p3 = ld4(pp + 12);
                a0.x += p0.x; a0.y += p0.y; a0.z += p0.z; a0.w += p0.w;
                a1.x += p1.x; a1.y += p1.y; a1.z += p1.z; a1.w += p1.w;
                a2.x += p2.x; a2.y += p2.y; a2.z += p2.z; a2.w += p2.w;
                a3.x += p3.x; a3.y += p3.y; a3.z += p3.z; a3.w += p3.w;
            }
        }

        // B fragments for this step (issue early; L2-hot)
        const int kb = k0 >> 5;
        bf16x8 b_h[4], b_l[4];
#pragma unroll
        for (int j = 0; j < 4; j++) {
            const int nb = (n0 + wn * 64 + j * 16) >> 4;
            const size_t boff = ((size_t)(nb * KB + kb) * 64 + lane) * 8;
            b_h[j] = *reinterpret_cast<const bf16x8*>(Whi + boff);
            b_l[j] = *reinterpret_cast<const bf16x8*>(Wlo + boff);
        }

        // A fragments from LDS buf[cur]
        bf16x8 a_h[4], a_l[4];
#pragma unroll
        for (int i = 0; i < 4; i++) {
            int f = (wm * 64 + i * 16 + lr) * 4 + lg;
            int o = swz(f) * 8;
            a_h[i] = *reinterpret_cast<const bf16x8*>(sAh[cur] + o);
            a_l[i] = *reinterpret_cast<const bf16x8*>(sAl[cur] + o);
        }

#pragma unroll
        for (int j = 0; j < 4; j++) {
#pragma unroll
            for (int i = 0; i < 4; i++) {
                acc[i][j] = __builtin_amdgcn_mfma_f32_16x16x32_bf16(a_h[i], b_l[j], acc[i][j], 0, 0, 0);
                acc[i][j] = __builtin_amdgcn_mfma_f32_16x16x32_bf16(a_l[i], b_h[j], acc[i][j], 0, 0, 0);
                acc[i][j] = __builtin_amdgcn_mfma_f32_16x16x32_bf16(a_h[i], b_h[j], acc[i][j], 0, 0, 0);
            }
        }

        // write next step's A into the other buffer; one barrier per step.
        // (safe: buf[cur^1] was last read at step k-1, protected by that
        //  step's barrier; this step's barrier orders the write before the
        //  step k+1 reads.)
        if (more) {
            u16x8 h0, l0, h1, l1;
            split8(a0, a1, h0, l0);
            split8(a2, a3, h1, l1);
            *reinterpret_cast<u16x8*>(sAh[cur ^ 1] + swz(f0) * 8) = h0;
            *reinterpret_cast<u16x8*>(sAl[cur ^ 1] + swz(f0) * 8) = l0;
            *reinterpret_cast<u16x8*>(sAh[cur ^ 1] + swz(f0 + 1) * 8) = h1;
            *reinterpret_cast<u16x8*>(sAl[cur ^ 1] + swz(f0 + 1) * 8) = l1;
            __syncthreads();
            cur ^= 1;
        }
    }

    // epilogue: D[col = lane&15, row = 4*(lane>>4)+reg] (m89-verified layout)
    float bj[4];
#pragma unroll
    for (int j = 0; j < 4; j++) bj[j] = bias[n0 + wn * 64 + j * 16 + lr];
    const int cbase = ncol + wn * 64 + lr;

#pragma unroll
    for (int i = 0; i < 4; i++) {
        size_t rbase[4];
#pragma unroll
        for (int rg = 0; rg < 4; rg++) {
            int rr = m0 + wm * 64 + i * 16 + lg * 4 + rg;
            if (MODE == 2) {
                int w = rr / V_VAL, vv = rr - w * V_VAL;
                rbase[rg] = (size_t)winds[w * T_WIN + vv] * C_DIM;
            } else if (MODE == 1) {
                rbase[rg] = (size_t)rr * C_DIM;
            } else {
                rbase[rg] = (size_t)rr * (size_t)Nc;
            }
        }
#pragma unroll
        for (int j = 0; j < 4; j++) {
#pragma unroll
            for (int rg = 0; rg < 4; rg++) {
                float t = acc[i][j][rg] + bj[j];
                if (MODE == 3) t = 0.5f * t * (1.f + erff(t * 0.70710678118654752f));
                outp[rbase[rg] + cbase + j * 16] = t;
            }
        }
    }
}

// one block per (window, head); q/k/v are [N, C] window-major fp32; o overwrites q
__global__ __launch_bounds__(256)
void attn_win(float* __restrict__ q, const float* __restrict__ k, const float* __restrict__ v)
{
    __shared__ float qs[V_VAL][D_HEAD + 1];
    __shared__ float ks[V_VAL][D_HEAD + 1];
    __shared__ float vs[V_VAL][D_HEAD + 1];
    __shared__ float ss[V_VAL][V_VAL + 1];
    const int tid = threadIdx.x;
    const int wid = blockIdx.x >> 3;
    const int h = blockIdx.x & 7;
    const size_t base = (size_t)(wid * V_VAL) * C_DIM + h * D_HEAD;

    for (int e = tid; e < V_VAL * D_HEAD; e += 256) {
        int t = e >> 5, d = e & 31;
        size_t src = base + (size_t)t * C_DIM + d;
        qs[t][d] = q[src];
        ks[t][d] = k[src];
        vs[t][d] = v[src];
    }
    __syncthreads();

    const int si = (tid >> 4) * 3, sj = (tid & 15) * 3;
    float a00=0,a01=0,a02=0,a10=0,a11=0,a12=0,a20=0,a21=0,a22=0;
#pragma unroll
    for (int kk = 0; kk < D_HEAD; kk++) {
        float q0 = qs[si][kk], q1 = qs[si+1][kk], q2 = qs[si+2][kk];
        float k0 = ks[sj][kk], k1 = ks[sj+1][kk], k2 = ks[sj+2][kk];
        a00 += q0*k0; a01 += q0*k1; a02 += q0*k2;
        a10 += q1*k0; a11 += q1*k1; a12 += q1*k2;
        a20 += q2*k0; a21 += q2*k1; a22 += q2*k2;
    }
    const float scale = 0.17677669529663687f;
    ss[si  ][sj] = a00*scale; ss[si  ][sj+1] = a01*scale; ss[si  ][sj+2] = a02*scale;
    ss[si+1][sj] = a10*scale; ss[si+1][sj+1] = a11*scale; ss[si+1][sj+2] = a12*scale;
    ss[si+2][sj] = a20*scale; ss[si+2][sj+1] = a21*scale; ss[si+2][sj+2] = a22*scale;
    __syncthreads();

    if (tid < V_VAL) {
        float m = -1e30f;
        for (int j = 0; j < V_VAL; j++) m = fmaxf(m, ss[tid][j]);
        float sum = 0.f;
        for (int j = 0; j < V_VAL; j++) {
            float e = expf(ss[tid][j] - m);
            ss[tid][j] = e;
            sum += e;
        }
        float inv = 1.f / sum;
        for (int j = 0; j < V_VAL; j++) ss[tid][j] *= inv;
    }
    __syncthreads();

    const int oi = (tid >> 4) * 3, oj = (tid & 15) * 2;
    float o00=0,o01=0,o10=0,o11=0,o20=0,o21=0;
#pragma unroll 4
    for (int t = 0; t < V_VAL; t++) {
        float p0 = ss[oi][t], p1 = ss[oi+1][t], p2 = ss[oi+2][t];
        float v0 = vs[t][oj], v1 = vs[t][oj+1];
        o00 += p0*v0; o01 += p0*v1;
        o10 += p1*v0; o11 += p1*v1;
        o20 += p2*v0; o21 += p2*v1;
    }
    q[base + (size_t)(oi  ) * C_DIM + oj] = o00; q[base + (size_t)(oi  ) * C_DIM + oj + 1] = o01;
    q[base + (size_t)(oi+1) * C_DIM + oj] = o10; q[base + (size_t)(oi+1) * C_DIM + oj + 1] = o11;
    q[base + (size_t)(oi+2) * C_DIM + oj] = o20; q[base + (size_t)(oi+2) * C_DIM + oj + 1] = o21;
}

// out = LayerNorm(x + r) * s + b ; one wave per 256-wide row (in-place safe)
__global__ __launch_bounds__(256)
void ln_res(const float* __restrict__ x, const float* __restrict__ r,
            const float* __restrict__ s, const float* __restrict__ b,
            float* __restrict__ out)
{
    const int row = blockIdx.x * 4 + (threadIdx.x >> 6);
    const int lane = threadIdx.x & 63;
    const size_t off = (size_t)row * C_DIM + lane * 4;
    float4 xv = ld4(x + off);
    float4 rv = ld4(r + off);
    float tx = xv.x + rv.x, ty = xv.y + rv.y, tz = xv.z + rv.z, tw = xv.w + rv.w;
    float sum = tx + ty + tz + tw;
#pragma unroll
    for (int m = 32; m >= 1; m >>= 1) sum += __shfl_xor(sum, m, 64);
    const float mean = sum * (1.0f / 256.0f);
    float dx = tx - mean, dy = ty - mean, dz = tz - mean, dw = tw - mean;
    float sq = dx*dx + dy*dy + dz*dz + dw*dw;
#pragma unroll
    for (int m = 32; m >= 1; m >>= 1) sq += __shfl_xor(sq, m, 64);
    const float inv = rsqrtf(sq * (1.0f / 256.0f) + 1e-5f);
    const int c = lane * 4;
    float4 sv = ld4(s + c);
    float4 bv = ld4(b + c);
    float4 o;
    o.x = dx * inv * sv.x + bv.x;
    o.y = dy * inv * sv.y + bv.y;
    o.z = dz * inv * sv.z + bv.z;
    o.w = dw * inv * sv.w + bv.w;
    *reinterpret_cast<float4*>(out + off) = o;
}

extern "C" void kernel_launch(void* const* d_in, const int* in_sizes, int n_in,
                              void* d_out, int out_size, void* d_ws, size_t ws_size,
                              hipStream_t stream)
{
    const float* feat_in = (const float*)d_in[0];
    const float* pos     = (const float*)d_in[1];
    const int*   winds   = (const int*)d_in[2];
    // d_in[3] = padding_mask (unused: pad iff t >= V)
    const float* ipw = (const float*)d_in[4];
    const float* ipb = (const float*)d_in[5];
    const float* opw = (const float*)d_in[6];
    const float* opb = (const float*)d_in[7];
    const float* l1w = (const float*)d_in[8];
    const float* l1b = (const float*)d_in[9];
    const float* l2w = (const float*)d_in[10];
    const float* l2b = (const float*)d_in[11];
    const float* n1s = (const float*)d_in[12];
    const float* n1b = (const float*)d_in[13];
    const float* n2s = (const float*)d_in[14];
    const float* n2b = (const float*)d_in[15];

    float* feat_out = (float*)d_out;
    float* ws = (float*)d_ws;

    // Arena (peak 3*nc + 6 MB ~= 308 MB):
    //   attn phase: q(0..nc) kbuf(nc..2nc) vbuf(2nc..3nc); aseq reuses kbuf slot
    //   ffn phase (2 half-N chunks): mid(0..2nc) tmp(2nc..2.5nc)
    //   weights: hi/lo arenas at 3nc.
    const size_t nc = (size_t)N_VOX * C_DIM;   // 25165824 floats
    float* q    = ws;
    float* kbuf = ws + nc;
    float* vbuf = ws + 2 * nc;
    float* aseq = kbuf;
    float* mid  = ws;
    float* tmp  = ws + 2 * nc;

    unsigned short* whi = (unsigned short*)(ws + 3 * nc);
    unsigned short* wlo = whi + 1572864;

    const dim3 blk256(256);
    const int NH = N_VOX / 2;                  // FFN chunk rows

    // weights -> fragment-ordered split bf16 (every call; ws is re-poisoned)
    conv_weights<<<dim3(768), blk256, 0, stream>>>(ipw, opw, l1w, l2w, whi, wlo);

    for (int l = 0; l < 2; l++) {
        const float* fin = (l == 0) ? feat_in : feat_out;
        const int*   wl  = winds + (size_t)l * W_NUM * T_WIN;
        const float* pl  = pos + (size_t)l * W_NUM * T_WIN * C_DIM;

        const unsigned short* ipw_h = whi + (size_t)l * 196608;
        const unsigned short* ipw_l = wlo + (size_t)l * 196608;
        const unsigned short* opw_h = whi + 393216 + (size_t)l * 65536;
        const unsigned short* opw_l = wlo + 393216 + (size_t)l * 65536;
        const unsigned short* l1w_h = whi + 524288 + (size_t)l * 262144;
        const unsigned short* l1w_l = wlo + 524288 + (size_t)l * 262144;
        const unsigned short* l2w_h = whi + 1048576 + (size_t)l * 262144;
        const unsigned short* l2w_l = wlo + 1048576 + (size_t)l * 262144;

        // QKV projection (gather + pos fused); 128-col blocks over 768 cols
        gemm_mfma<1><<<dim3(768, 6), blk256, 0, stream>>>(
            nullptr, fin, wl, pl, ipw_h, ipw_l,
            ipb + (size_t)l * 3 * C_DIM, q, kbuf, vbuf, 3 * C_DIM, C_DIM);

        // windowed attention (o overwrites q)
        attn_win<<<dim3(W_NUM * H_NUM), blk256, 0, stream>>>(q, kbuf, vbuf);

        // out projection, scattered back to sequence order (aseq = kbuf slot)
        gemm_mfma<2><<<dim3(768, 2), blk256, 0, stream>>>(
            q, nullptr, wl, nullptr, opw_h, opw_l,
            opb + (size_t)l * C_DIM, aseq, nullptr, nullptr, C_DIM, C_DIM);

        // LN1(feat + attn)
        ln_res<<<dim3(N_VOX / 4), blk256, 0, stream>>>(
            fin, aseq, n1s + (size_t)l * C_DIM, n1b + (size_t)l * C_DIM, feat_out);

        // FFN in two half-N chunks to cap workspace
        for (int c = 0; c < 2; c++) {
            const float* fchunk = feat_out + (size_t)c * NH * C_DIM;
            // up + gelu: [NH, C] x [F, C]^T -> mid [NH, F]
            gemm_mfma<3><<<dim3(NH / 128, F_DIM / 128), blk256, 0, stream>>>(
                fchunk, nullptr, nullptr, nullptr, l1w_h, l1w_l,
                l1b + (size_t)l * F_DIM, mid, nullptr, nullptr, F_DIM, C_DIM);
            // down: [NH, F] x [C, F]^T -> tmp [NH, C]
            gemm_mfma<0><<<dim3(NH / 128, C_DIM / 128), blk256, 0, stream>>>(
                mid, nullptr, nullptr, nullptr, l2w_h, l2w_l,
                l2b + (size_t)l * C_DIM, tmp, nullptr, nullptr, C_DIM, F_DIM);
            // LN2(feat + ffn) on the chunk
            ln_res<<<dim3(NH / 4), blk256, 0, stream>>>(
                fchunk, tmp, n2s + (size_t)l * C_DIM, n2b + (size_t)l * C_DIM,
                feat_out + (size_t)c * NH * C_DIM);
        }
    }
}